// Round 1
// baseline (727.206 us; speedup 1.0000x reference)
//
#include <hip/hip_runtime.h>
#include <stdint.h>

typedef unsigned short u16;
typedef __attribute__((ext_vector_type(4))) float f32x4;
typedef __attribute__((ext_vector_type(8))) short short8;
typedef __attribute__((ext_vector_type(4))) unsigned short u16x4;
typedef __attribute__((ext_vector_type(4))) int int4v;

__device__ __forceinline__ u16 f2b(float f) {
  uint32_t u = __float_as_uint(f);
  uint32_t r = (u + 0x7fffu + ((u >> 16) & 1u)) >> 16;   // RNE
  return (u16)r;
}
__device__ __forceinline__ float b2f(u16 b) {
  return __uint_as_float(((uint32_t)b) << 16);
}
__device__ __forceinline__ float sigm(float x) { return 1.f / (1.f + __expf(-x)); }
__device__ __forceinline__ float tanh_fast(float x) {
  float e = __expf(2.f * x);
  return 1.f - 2.f / (e + 1.f);   // safe at +-inf
}
__device__ __forceinline__ void gl2lds16(const void* g, void* l) {
  __builtin_amdgcn_global_load_lds((const __attribute__((address_space(1))) void*)g,
                                   (__attribute__((address_space(3))) void*)l, 16, 0, 0);
}

// ---------------- elementwise fp32 -> bf16 (frames), now T-MAJOR rows ----------
// A_enc row = t*128 + b  (so one 128-row GEMM M-tile == one timestep)
__global__ void cvt_bf16_kernel(const float* __restrict__ in, u16* __restrict__ out, int n4) {
  int i = blockIdx.x * 256 + threadIdx.x;
  if (i >= n4) return;
  float4 v = ((const float4*)in)[i];
  int e = i * 4;                 // flat elem in [128][64][2048]
  int b = e >> 17;
  int t = (e >> 11) & 63;
  int d = e & 2047;
  size_t row = (size_t)t * 128 + b;
  u16x4 o = { f2b(v.x), f2b(v.y), f2b(v.z), f2b(v.w) };
  *(u16x4*)(out + row * 2048 + d) = o;
}

// ---------------- plain W transpose: WT[p][kc] = W[ko][p] (bf16) ----------------
__global__ void transpose_kernel(const float* __restrict__ W, u16* __restrict__ WT,
                                 int ldin, int ldout, int xreal, int xpad) {
  __shared__ float tile[64][65];
  const int kb = blockIdx.x * 64;
  const int pb = blockIdx.y * 64;
  const int t = threadIdx.x;
  const int pc = t & 63;
  const int kr4 = t >> 6;
#pragma unroll
  for (int it = 0; it < 16; ++it) {
    int kl = kr4 + it * 4;
    int kc = kb + kl;
    int ko = kc < xpad ? kc : kc - (xpad - xreal);
    bool valid = (kc < xreal) || (kc >= xpad);
    tile[kl][pc] = valid ? W[(size_t)ko * ldin + pb + pc] : 0.f;
  }
  __syncthreads();
  const int pl = t >> 2;
  const int kq = t & 3;
#pragma unroll
  for (int half = 0; half < 2; ++half) {
    union { short8 v; u16 a[8]; } pk;
#pragma unroll
    for (int i = 0; i < 8; ++i) pk.a[i] = f2b(tile[kq * 16 + half * 8 + i][pl]);
    *(short8*)&WT[(size_t)(pb + pl) * ldout + kb + kq * 16 + half * 8] = pk.v;
  }
}

// ---------------- W_out -> B^T bf16 [384][512] (rows >=300 zero) ----------------
__global__ void woutT_kernel(const float* __restrict__ Wout, u16* __restrict__ WT) {
  int idx = blockIdx.x * 256 + threadIdx.x;
  if (idx >= 384 * 512) return;
  int n = idx >> 9, k = idx & 511;
  float v = (n < 300) ? Wout[(size_t)k * 300 + n] : 0.f;
  WT[idx] = f2b(v);
}

// ---------------- embedding gather -> A_dec bf16 [4096][320] time-major ---------
__global__ void embed_kernel(const int* __restrict__ ids, const float* __restrict__ emb,
                             u16* __restrict__ Adec) {
  int r = blockIdx.x;              // r = t*128 + b
  int t = r >> 7, b = r & 127;
  int id = ids[b * 32 + t];
  const float* src = emb + (size_t)id * 300;
  u16* dst = Adec + (size_t)r * 320;
  for (int d = threadIdx.x; d < 320; d += 64)
    dst[d] = f2b(d < 300 ? src[d] : 0.f);
}

// ================= fused persistent kernel =================
// blocks 0..127          : LSTM recurrence (protocol as before, +dedicated storer wave)
// blocks 128..1151       : encoder pre-GEMM, t-major (t = (bid-128)>>4, nt = &15)
// blocks 1152..1663      : decoder pre-GEMM, t-major
// Producers write pre via sc0sc1 stores, drain, then atomicAdd(pf[t]) (agent).
// Consumers poll pf[t]==16 BEFORE issuing sc0sc1 pre loads (data-after-flag).
struct SmemLstm { u16 wlds[128][520]; u16 stage[2][16][32]; };
struct SmemGemm { u16 at[2][128 * 32]; u16 bt[2][128 * 32]; };
union SmemU { SmemLstm l; SmemGemm g; };

__global__ __launch_bounds__(256)
void mega_kernel(const u16* __restrict__ A_enc, const u16* __restrict__ WencT,
                 u16* __restrict__ pre_enc, const float* __restrict__ b_enc,
                 const u16* __restrict__ A_dec, const u16* __restrict__ WdecT,
                 u16* __restrict__ pre_dec, const float* __restrict__ b_dec,
                 int* __restrict__ hbuf, u16* __restrict__ dec_hs,
                 int* __restrict__ flags, int* __restrict__ pf_enc,
                 int* __restrict__ pf_dec) {
  __shared__ SmemU sm;
  const int bid = blockIdx.x;
  const int tid = threadIdx.x;
  const int lane = tid & 63;

  if (bid < 128) {
    // ------------------ LSTM block (4 waves: 0,1 compute; 2 store; 3 idle) ------
    const int hb = tid >> 6;
    const int bg = bid & 7;
    const int hg = bid >> 3;
    const int colq = lane & 15;
    const int rquad = lane >> 4;

    for (int i = tid; i < 128 * 64; i += 256) {
      int lr = i >> 6, cc = i & 63;
      const u16* src = WencT + (size_t)((lr >> 5) * 512 + hg * 32 + (lr & 31)) * 2560 + 2048;
      *(short8*)&sm.l.wlds[lr][cc * 8] = *(const short8*)(src + cc * 8);
    }
    __syncthreads();

    float cst[4] = {0.f, 0.f, 0.f, 0.f};
    const int brow = bg * 16 + rquad * 4;
    const int pbase = hg * 32 + (hb & 1) * 16 + colq;
    union HV { int4v i; short8 s; };

    for (int s = 0; s < 96; ++s) {
      const bool dec = (s >= 64);
      const int sb = s & 1;
      if (hb < 2) {
        const u16* pre_t = dec ? (pre_dec + (size_t)(s - 64) * 262144)
                               : (pre_enc + (size_t)s * 262144);
        // 1) pre-activation readiness (16 producer n-tiles per timestep)
        int* pf = dec ? (pf_dec + (s - 64)) : (pf_enc + s);
        while (__hip_atomic_load(pf, __ATOMIC_RELAXED, __HIP_MEMORY_SCOPE_AGENT) != 16) {}
        asm volatile("" ::: "memory");
        // 2) pre loads (sc0 sc1: producer wrote through to LLC intra-kernel)
        int praw[4][4];
        const u16* p0 = pre_t + (size_t)brow * 2048 + pbase;
#pragma unroll
        for (int l = 0; l < 4; ++l)
#pragma unroll
          for (int r = 0; r < 4; ++r)
            asm volatile("global_load_ushort %0, %1, off sc0 sc1"
                         : "=v"(praw[l][r]) : "v"(p0 + (size_t)r * 2048 + l * 512) : "memory");
        // 3) h(s) flag wait: one producer flag per lane (flag-after-drain protocol)
        if (s > 0) {
          const int* fp = flags + ((size_t)s * 8 + bg) * 16 + (lane & 15);
          while (__hip_atomic_load(fp, __ATOMIC_RELAXED, __HIP_MEMORY_SCOPE_AGENT) == 0) {}
          asm volatile("" ::: "memory");
        }
        // 4) bulk h read, issued once, after flag observation
        HV hv[16];
        const int* hread = hbuf + (size_t)s * 32768 + bg * 4096 + colq * 16 + rquad * 4;
#pragma unroll
        for (int g = 0; g < 4; ++g) {
          const int* hp = hread + g * 1024;
#pragma unroll
          for (int q = 0; q < 4; ++q)
            asm volatile("global_load_dwordx4 %0, %1, off offset:%2 sc0 sc1"
                         : "=v"(hv[g * 4 + q].i) : "v"(hp), "i"(q * 1024) : "memory");
        }
        asm volatile("s_waitcnt vmcnt(0)" ::: "memory");
        __builtin_amdgcn_sched_barrier(0);
#pragma unroll
        for (int kt = 0; kt < 16; ++kt) asm volatile("" : "+v"(hv[kt].i));
#pragma unroll
        for (int l = 0; l < 4; ++l)
#pragma unroll
          for (int r = 0; r < 4; ++r) asm volatile("" : "+v"(praw[l][r]));
        // 5) acc init + h @ W_h
        f32x4 acc[4];
#pragma unroll
        for (int l = 0; l < 4; ++l)
#pragma unroll
          for (int r = 0; r < 4; ++r) acc[l][r] = b2f((u16)praw[l][r]);
#pragma unroll
        for (int kt = 0; kt < 16; ++kt) {
#pragma unroll
          for (int l = 0; l < 4; ++l) {
            short8 bf = *(const short8*)&sm.l.wlds[l * 32 + hb * 16 + colq][kt * 32 + rquad * 8];
            acc[l] = __builtin_amdgcn_mfma_f32_16x16x32_bf16(hv[kt].s, bf, acc[l], 0, 0, 0);
          }
        }
        // 6) elementwise: i,j,f,o in-lane
#pragma unroll
        for (int r = 0; r < 4; ++r) {
          float iv = acc[0][r], jv = acc[1][r], fv = acc[2][r], ov = acc[3][r];
          float cn = cst[r] * sigm(fv + 1.f) + sigm(iv) * tanh_fast(jv);
          cst[r] = cn;
          float hvv = tanh_fast(cn) * sigm(ov);
          sm.l.stage[sb][rquad * 4 + r][hb * 16 + colq] = f2b(hvv);
        }
      }
      __syncthreads();
      // 7) DEDICATED STORER WAVE: waves 0/1 proceed to step s+1 immediately;
      //    wave 2 pushes the 1KB h block, drains to LLC, sets the flag.
      if (hb == 2) {
        const int t2 = tid - 128;
        const int row = t2 >> 2, q = t2 & 3;
        union { short8 v; int4v i; } vv;
        vv.v = *(const short8*)&sm.l.stage[sb][row][q * 8];
        int* dst = hbuf + (size_t)(s + 1) * 32768 + bg * 4096 + hg * 256 + row * 16 + q * 4;
        asm volatile("global_store_dwordx4 %0, %1, off sc0 sc1"
                     :: "v"(dst), "v"(vv.i) : "memory");
        if (dec)
          *(short8*)&dec_hs[(size_t)(s - 64) * 65536 + (size_t)(bg * 16 + row) * 512 +
                            hg * 32 + q * 8] = vv.v;
        asm volatile("s_waitcnt vmcnt(0)" ::: "memory");   // data acked at LLC
        if (t2 == 0) {
          int* fp = flags + ((size_t)(s + 1) * 8 + bg) * 16 + hg;
          int one = 1;
          asm volatile("global_store_dword %0, %1, off sc0 sc1"
                       :: "v"(fp), "v"(one) : "memory");
        }
      }
      if (s == 63) {   // swap to decoder W_h (cols 320..831 of WdecT)
        for (int i = tid; i < 128 * 64; i += 256) {
          int lr = i >> 6, cc = i & 63;
          const u16* src = WdecT + (size_t)((lr >> 5) * 512 + hg * 32 + (lr & 31)) * 832 + 320;
          *(short8*)&sm.l.wlds[lr][cc * 8] = *(const short8*)(src + cc * 8);
        }
        __syncthreads();
      }
    }
    asm volatile("s_waitcnt vmcnt(0)" ::: "memory");
    return;
  }

  // ------------------ producer GEMM block (2-phase double-buffered) -------------
  int idx = bid - 128;
  const u16* A; const u16* BT; u16* C; const float* bias; int* flag;
  int lda, ldb, K, m0, n0;
  if (idx < 1024) {
    int t = idx >> 4, nt = idx & 15;
    A = A_enc; lda = 2048; BT = WencT; ldb = 2560; K = 2048;
    C = pre_enc; bias = b_enc; flag = pf_enc + t;
    m0 = t * 128; n0 = nt * 128;
  } else {
    idx -= 1024;
    int t = idx >> 4, nt = idx & 15;
    A = A_dec; lda = 320; BT = WdecT; ldb = 832; K = 320;
    C = pre_dec; bias = b_dec; flag = pf_dec + t;
    m0 = t * 128; n0 = nt * 128;
  }
  const int wave = tid >> 6;
  const int wm = wave & 1, wn = wave >> 1;
  const int colq = lane & 15, rquad = lane >> 4;

  f32x4 acc[4][4];
#pragma unroll
  for (int i = 0; i < 4; ++i)
#pragma unroll
    for (int j = 0; j < 4; ++j) { f32x4 z = {0.f, 0.f, 0.f, 0.f}; acc[i][j] = z; }

  auto stage_tile = [&](int buf, int k0) {
#pragma unroll
    for (int c = 0; c < 2; ++c) {
      const int ch = wave + c * 4;
      const int slot = ch * 64 + lane;
      const int m = slot >> 2;
      const int koff = (slot & 3) * 8;
      gl2lds16(A + (size_t)(m0 + m) * lda + k0 + koff, sm.g.at[buf] + ch * 512);
      gl2lds16(BT + (size_t)(n0 + m) * ldb + k0 + koff, sm.g.bt[buf] + ch * 512);
    }
  };

  stage_tile(0, 0);
  __builtin_amdgcn_s_waitcnt(0);
  __syncthreads();
  const int niter = K >> 5;
  for (int it = 0; it < niter; ++it) {
    const int cur = it & 1;
    if (it + 1 < niter) stage_tile(cur ^ 1, (it + 1) << 5);   // prefetch in flight
    short8 af[4], bf[4];
#pragma unroll
    for (int i = 0; i < 4; ++i)
      af[i] = *(const short8*)(sm.g.at[cur] + (wm * 64 + i * 16 + colq) * 32 + rquad * 8);
#pragma unroll
    for (int j = 0; j < 4; ++j)
      bf[j] = *(const short8*)(sm.g.bt[cur] + (wn * 64 + j * 16 + colq) * 32 + rquad * 8);
#pragma unroll
    for (int i = 0; i < 4; ++i)
#pragma unroll
      for (int j = 0; j < 4; ++j)
        acc[i][j] = __builtin_amdgcn_mfma_f32_16x16x32_bf16(af[i], bf[j], acc[i][j], 0, 0, 0);
    __builtin_amdgcn_s_waitcnt(0);   // next tile staged
    __syncthreads();
  }

  // epilogue: sc0sc1 stores (intra-kernel cross-XCD visibility), drain, flag
  const int gm_base = m0 + wm * 64;
  const int gn_base = n0 + wn * 64;
#pragma unroll
  for (int i = 0; i < 4; ++i) {
#pragma unroll
    for (int j = 0; j < 4; ++j) {
      const int gn = gn_base + j * 16 + colq;
      const float bv = bias[gn];
      const int rbase = gm_base + i * 16 + rquad * 4;
#pragma unroll
      for (int r = 0; r < 4; ++r) {
        int hv16 = (int)f2b(acc[i][j][r] + bv);
        const u16* addr = C + (size_t)(rbase + r) * 2048 + gn;
        asm volatile("global_store_short %0, %1, off sc0 sc1"
                     :: "v"(addr), "v"(hv16) : "memory");
      }
    }
  }
  asm volatile("s_waitcnt vmcnt(0)" ::: "memory");
  __syncthreads();
  if (tid == 0)
    __hip_atomic_fetch_add(flag, 1, __ATOMIC_RELAXED, __HIP_MEMORY_SCOPE_AGENT);
}

// ---------------- output projection: C = dec_hs @ WoutT^T (fp32 out) ------------
__global__ __launch_bounds__(256)
void out_gemm_kernel(const u16* __restrict__ A, const u16* __restrict__ BT,
                     float* __restrict__ Cv, const float* __restrict__ bias) {
  const int lda = 512, ldb = 512, K = 512;
  __shared__ u16 atile[128 * 32];
  __shared__ u16 btile[128 * 32];
  const int tid = threadIdx.x;
  const int wave = tid >> 6;
  const int lane = tid & 63;
  const int m0 = blockIdx.x * 128;
  const int n0 = blockIdx.y * 128;
  const int wm = wave & 1;
  const int wn = wave >> 1;
  const int colq = lane & 15;
  const int rquad = lane >> 4;

  f32x4 acc[4][4];
#pragma unroll
  for (int i = 0; i < 4; ++i)
#pragma unroll
    for (int j = 0; j < 4; ++j) { f32x4 z = {0.f, 0.f, 0.f, 0.f}; acc[i][j] = z; }

  for (int k0 = 0; k0 < K; k0 += 32) {
#pragma unroll
    for (int c = 0; c < 2; ++c) {
      const int ch = wave + c * 4;
      const int slot = ch * 64 + lane;
      const int m = slot >> 2;
      const int koff = (slot & 3) * 8;
      gl2lds16(A + (size_t)(m0 + m) * lda + k0 + koff, atile + ch * 512);
      gl2lds16(BT + (size_t)(n0 + m) * ldb + k0 + koff, btile + ch * 512);
    }
    __builtin_amdgcn_s_waitcnt(0);
    __syncthreads();
    short8 af[4], bf[4];
#pragma unroll
    for (int i = 0; i < 4; ++i)
      af[i] = *(const short8*)(atile + (wm * 64 + i * 16 + colq) * 32 + rquad * 8);
#pragma unroll
    for (int j = 0; j < 4; ++j)
      bf[j] = *(const short8*)(btile + (wn * 64 + j * 16 + colq) * 32 + rquad * 8);
#pragma unroll
    for (int i = 0; i < 4; ++i)
#pragma unroll
      for (int j = 0; j < 4; ++j)
        acc[i][j] = __builtin_amdgcn_mfma_f32_16x16x32_bf16(af[i], bf[j], acc[i][j], 0, 0, 0);
    __syncthreads();
  }

  const int gm_base = m0 + wm * 64;
  const int gn_base = n0 + wn * 64;
#pragma unroll
  for (int i = 0; i < 4; ++i) {
#pragma unroll
    for (int j = 0; j < 4; ++j) {
      const int gn = gn_base + j * 16 + colq;
      const float bv = (gn < 300) ? bias[gn] : 0.f;
      const int rbase = gm_base + i * 16 + rquad * 4;
#pragma unroll
      for (int r = 0; r < 4; ++r) {
        const float v = acc[i][j][r] + bv;
        const int row = rbase + r;
        if (gn < 300)
          Cv[(size_t)((row & 127) * 32 + (row >> 7)) * 300 + gn] = v;
      }
    }
  }
}

extern "C" void kernel_launch(void* const* d_in, const int* in_sizes, int n_in,
                              void* d_out, int out_size, void* d_ws, size_t ws_size,
                              hipStream_t stream) {
  const float* frames = (const float*)d_in[0];   // [128,64,2048]
  const int* cap_ids  = (const int*)d_in[1];     // [128,32]
  const float* emb    = (const float*)d_in[2];   // [32000,300]
  const float* W_enc  = (const float*)d_in[3];   // [2560,2048]
  const float* b_enc  = (const float*)d_in[4];   // [2048]
  const float* W_dec  = (const float*)d_in[5];   // [812,2048]
  const float* b_dec  = (const float*)d_in[6];   // [2048]
  const float* W_out  = (const float*)d_in[7];   // [512,300]
  const float* b_out  = (const float*)d_in[8];   // [300]
  float* out = (float*)d_out;

  char* ws = (char*)d_ws;
  size_t off = 0;
  auto alloc = [&](size_t bytes) {
    void* p = ws + off;
    off += (bytes + 255) & ~(size_t)255;
    return p;
  };
  u16* A_enc   = (u16*)alloc(8192ull * 2048 * 2);
  u16* WencT   = (u16*)alloc(2048ull * 2560 * 2);
  u16* pre_enc = (u16*)alloc(64ull * 128 * 2048 * 2);
  u16* A_dec   = (u16*)alloc(4096ull * 320 * 2);
  u16* WdecT   = (u16*)alloc(2048ull * 832 * 2);
  u16* pre_dec = (u16*)alloc(32ull * 128 * 2048 * 2);
  u16* WoutT   = (u16*)alloc(384ull * 512 * 2);
  u16* dec_hs  = (u16*)alloc(32ull * 128 * 512 * 2);
  int* hbuf    = (int*)alloc(97ull * 32768 * 4);
  int* flags   = (int*)alloc(97ull * 8 * 16 * 4);
  int* pf      = (int*)alloc(96ull * 4);          // [64] enc + [32] dec t-flags
  int* pf_enc  = pf;
  int* pf_dec  = pf + 64;

  hipMemsetAsync(hbuf, 0, 32768ull * 4, stream);
  hipMemsetAsync(flags, 0, 97ull * 8 * 16 * 4, stream);
  hipMemsetAsync(pf, 0, 96ull * 4, stream);

  cvt_bf16_kernel<<<16384, 256, 0, stream>>>(frames, A_enc, 4194304);
  transpose_kernel<<<dim3(40, 32), 256, 0, stream>>>(W_enc, WencT, 2048, 2560, 2048, 2048);
  transpose_kernel<<<dim3(13, 32), 256, 0, stream>>>(W_dec, WdecT, 2048, 832, 300, 320);
  woutT_kernel<<<768, 256, 0, stream>>>(W_out, WoutT);
  embed_kernel<<<4096, 64, 0, stream>>>(cap_ids, emb, A_dec);

  // fused: 128 LSTM blocks + 1024 enc-GEMM + 512 dec-GEMM producer blocks
  mega_kernel<<<1664, 256, 0, stream>>>(A_enc, WencT, pre_enc, b_enc,
                                        A_dec, WdecT, pre_dec, b_dec,
                                        hbuf, dec_hs, flags, pf_enc, pf_dec);

  out_gemm_kernel<<<dim3(32, 3), 256, 0, stream>>>(dec_hs, WoutT, out, b_out);
}

// Round 2
// 667.334 us; speedup vs baseline: 1.0897x; 1.0897x over previous
//
#include <hip/hip_runtime.h>
#include <stdint.h>

typedef unsigned short u16;
typedef __attribute__((ext_vector_type(4))) float f32x4;
typedef __attribute__((ext_vector_type(8))) short short8;
typedef __attribute__((ext_vector_type(4))) unsigned short u16x4;
typedef __attribute__((ext_vector_type(4))) int int4v;

__device__ __forceinline__ u16 f2b(float f) {
  uint32_t u = __float_as_uint(f);
  uint32_t r = (u + 0x7fffu + ((u >> 16) & 1u)) >> 16;   // RNE
  return (u16)r;
}
__device__ __forceinline__ float b2f(u16 b) {
  return __uint_as_float(((uint32_t)b) << 16);
}
__device__ __forceinline__ float sigm(float x) { return 1.f / (1.f + __expf(-x)); }
__device__ __forceinline__ float tanh_fast(float x) {
  float e = __expf(2.f * x);
  return 1.f - 2.f / (e + 1.f);   // safe at +-inf
}
__device__ __forceinline__ void gl2lds16(const void* g, void* l) {
  __builtin_amdgcn_global_load_lds((const __attribute__((address_space(1))) void*)g,
                                   (__attribute__((address_space(3))) void*)l, 16, 0, 0);
}

// ================= merged prep kernel =================
// class 0: cvt frames fp32 -> bf16 t-major          blocks [0, 16384)
// class 1: transpose W_enc -> WencT                 blocks [16384, 17664)  40x32
// class 2: transpose W_dec -> WdecT                 blocks [17664, 18080)  13x32
// class 3: W_out -> WoutT [384][512]                blocks [18080, 18848)
// class 4: embed gather -> A_dec                    blocks [18848, 19872)  4 rows/blk
__global__ __launch_bounds__(256)
void prep_kernel(const float* __restrict__ frames, u16* __restrict__ A_enc,
                 const float* __restrict__ W_enc, u16* __restrict__ WencT,
                 const float* __restrict__ W_dec, u16* __restrict__ WdecT,
                 const float* __restrict__ W_out, u16* __restrict__ WoutT,
                 const int* __restrict__ ids, const float* __restrict__ emb,
                 u16* __restrict__ Adec) {
  __shared__ float tile[64][65];
  const int bid = blockIdx.x;
  const int tid = threadIdx.x;

  if (bid < 16384) {
    // ---- cvt: A_enc row = t*128 + b ----
    int i = bid * 256 + tid;
    float4 v = ((const float4*)frames)[i];
    int e = i * 4;                 // flat elem in [128][64][2048]
    int b = e >> 17;
    int t = (e >> 11) & 63;
    int d = e & 2047;
    size_t row = (size_t)t * 128 + b;
    u16x4 o = { f2b(v.x), f2b(v.y), f2b(v.z), f2b(v.w) };
    *(u16x4*)(A_enc + row * 2048 + d) = o;
    return;
  }

  const float* W; u16* WT; int ldin, ldout, xreal, xpad, bx, by;
  if (bid < 18080) {
    if (bid < 17664) {
      int idx = bid - 16384;
      W = W_enc; WT = WencT; ldin = 2048; ldout = 2560; xreal = 2048; xpad = 2048;
      bx = idx % 40; by = idx / 40;
    } else {
      int idx = bid - 17664;
      W = W_dec; WT = WdecT; ldin = 2048; ldout = 832; xreal = 300; xpad = 320;
      bx = idx % 13; by = idx / 13;
    }
    const int kb = bx * 64;
    const int pb = by * 64;
    const int pc = tid & 63;
    const int kr4 = tid >> 6;
#pragma unroll
    for (int it = 0; it < 16; ++it) {
      int kl = kr4 + it * 4;
      int kc = kb + kl;
      int ko = kc < xpad ? kc : kc - (xpad - xreal);
      bool valid = (kc < xreal) || (kc >= xpad);
      tile[kl][pc] = valid ? W[(size_t)ko * ldin + pb + pc] : 0.f;
    }
    __syncthreads();
    const int pl = tid >> 2;
    const int kq = tid & 3;
#pragma unroll
    for (int half = 0; half < 2; ++half) {
      union { short8 v; u16 a[8]; } pk;
#pragma unroll
      for (int i = 0; i < 8; ++i) pk.a[i] = f2b(tile[kq * 16 + half * 8 + i][pl]);
      *(short8*)&WT[(size_t)(pb + pl) * ldout + kb + kq * 16 + half * 8] = pk.v;
    }
    return;
  }

  if (bid < 18848) {
    // ---- W_out -> B^T bf16 [384][512] ----
    int idx = (bid - 18080) * 256 + tid;
    int n = idx >> 9, k = idx & 511;
    float v = (n < 300) ? W_out[(size_t)k * 300 + n] : 0.f;
    WoutT[idx] = f2b(v);
    return;
  }

  // ---- embed gather: 4 rows per block ----
  int r = (bid - 18848) * 4 + (tid >> 6);   // r = t*128 + b
  int t = r >> 7, b = r & 127;
  int id = ids[b * 32 + t];
  const float* src = emb + (size_t)id * 300;
  u16* dst = Adec + (size_t)r * 320;
  for (int d = tid & 63; d < 320; d += 64)
    dst[d] = f2b(d < 300 ? src[d] : 0.f);
}

// ================= fused persistent kernel =================
// blocks 0..127     : LSTM recurrence (flag-after-drain protocol, dedicated storer wave)
// blocks 128..1151  : encoder pre-GEMM, t-major (t = (bid-128)>>4, nt = &15)
// blocks 1152..1663 : decoder pre-GEMM, t-major
// blocks 1664..1759 : output projection (waits on flags[t+65] row, i.e. dec_hs[t] drained)
// Producers write pre via sc0sc1 stores, drain, then atomicAdd(pf[t]) (agent).
// Consumers poll pf[t]==16 BEFORE issuing sc0sc1 pre loads (data-after-flag).
struct SmemLstm { u16 wlds[128][520]; u16 stage[2][16][32]; };
struct SmemGemm { u16 at[4][128 * 32]; u16 bt[4][128 * 32]; };   // 4-deep pipeline
union SmemU { SmemLstm l; SmemGemm g; };

__global__ __launch_bounds__(256)
void mega_kernel(const u16* __restrict__ A_enc, const u16* __restrict__ WencT,
                 u16* __restrict__ pre_enc, const float* __restrict__ b_enc,
                 const u16* __restrict__ A_dec, const u16* __restrict__ WdecT,
                 u16* __restrict__ pre_dec, const float* __restrict__ b_dec,
                 const u16* __restrict__ WoutT, const float* __restrict__ b_out,
                 float* __restrict__ outp,
                 int* __restrict__ hbuf, u16* __restrict__ dec_hs,
                 int* __restrict__ flags, int* __restrict__ pf_enc,
                 int* __restrict__ pf_dec) {
  __shared__ SmemU sm;
  const int bid = blockIdx.x;
  const int tid = threadIdx.x;
  const int lane = tid & 63;

  if (bid < 128) {
    // ------------------ LSTM block (waves 0,1 compute; 2 store; 3 idle) ---------
    const int hb = tid >> 6;
    const int bg = bid & 7;
    const int hg = bid >> 3;
    const int colq = lane & 15;
    const int rquad = lane >> 4;

    for (int i = tid; i < 128 * 64; i += 256) {
      int lr = i >> 6, cc = i & 63;
      const u16* src = WencT + (size_t)((lr >> 5) * 512 + hg * 32 + (lr & 31)) * 2560 + 2048;
      *(short8*)&sm.l.wlds[lr][cc * 8] = *(const short8*)(src + cc * 8);
    }
    __syncthreads();

    float cst[4] = {0.f, 0.f, 0.f, 0.f};
    const int brow = bg * 16 + rquad * 4;
    const int pbase = hg * 32 + (hb & 1) * 16 + colq;
    union HV { int4v i; short8 s; };
    int pf_next = 0;   // prefetched pf value for the upcoming step (0 => must poll)

    for (int s = 0; s < 96; ++s) {
      const bool dec = (s >= 64);
      const int sb = s & 1;
      if (hb < 2) {
        const u16* pre_t = dec ? (pre_dec + (size_t)(s - 64) * 262144)
                               : (pre_enc + (size_t)s * 262144);
        // 1) pre-activation readiness (16 producer n-tiles per timestep)
        if (pf_next != 16) {
          int* pf = dec ? (pf_dec + (s - 64)) : (pf_enc + s);
          while (__hip_atomic_load(pf, __ATOMIC_RELAXED, __HIP_MEMORY_SCOPE_AGENT) != 16) {}
        }
        asm volatile("" ::: "memory");
        // 2) pre loads (sc0 sc1: producer wrote through to LLC intra-kernel)
        int praw[4][4];
        const u16* p0 = pre_t + (size_t)brow * 2048 + pbase;
#pragma unroll
        for (int l = 0; l < 4; ++l)
#pragma unroll
          for (int r = 0; r < 4; ++r)
            asm volatile("global_load_ushort %0, %1, off sc0 sc1"
                         : "=v"(praw[l][r]) : "v"(p0 + (size_t)r * 2048 + l * 512) : "memory");
        // 3) h(s) flag wait: one producer flag per lane (flag-after-drain protocol)
        if (s > 0) {
          const int* fp = flags + ((size_t)s * 8 + bg) * 16 + (lane & 15);
          while (__hip_atomic_load(fp, __ATOMIC_RELAXED, __HIP_MEMORY_SCOPE_AGENT) == 0) {}
          asm volatile("" ::: "memory");
        }
        // 4) bulk h read, issued once, after flag observation
        HV hv[16];
        const int* hread = hbuf + (size_t)s * 32768 + bg * 4096 + colq * 16 + rquad * 4;
#pragma unroll
        for (int g = 0; g < 4; ++g) {
          const int* hp = hread + g * 1024;
#pragma unroll
          for (int q = 0; q < 4; ++q)
            asm volatile("global_load_dwordx4 %0, %1, off offset:%2 sc0 sc1"
                         : "=v"(hv[g * 4 + q].i) : "v"(hp), "i"(q * 1024) : "memory");
        }
        // prefetch next step's pf flag; rides the same vmcnt(0) drain below
        if (s + 1 < 96) {
          const int* pfn = (s + 1 >= 64) ? (pf_dec + (s + 1 - 64)) : (pf_enc + (s + 1));
          pf_next = __hip_atomic_load(pfn, __ATOMIC_RELAXED, __HIP_MEMORY_SCOPE_AGENT);
        }
        asm volatile("s_waitcnt vmcnt(0)" ::: "memory");
        __builtin_amdgcn_sched_barrier(0);
#pragma unroll
        for (int kt = 0; kt < 16; ++kt) asm volatile("" : "+v"(hv[kt].i));
#pragma unroll
        for (int l = 0; l < 4; ++l)
#pragma unroll
          for (int r = 0; r < 4; ++r) asm volatile("" : "+v"(praw[l][r]));
        // 5) acc init + h @ W_h
        f32x4 acc[4];
#pragma unroll
        for (int l = 0; l < 4; ++l)
#pragma unroll
          for (int r = 0; r < 4; ++r) acc[l][r] = b2f((u16)praw[l][r]);
#pragma unroll
        for (int kt = 0; kt < 16; ++kt) {
#pragma unroll
          for (int l = 0; l < 4; ++l) {
            short8 bf = *(const short8*)&sm.l.wlds[l * 32 + hb * 16 + colq][kt * 32 + rquad * 8];
            acc[l] = __builtin_amdgcn_mfma_f32_16x16x32_bf16(hv[kt].s, bf, acc[l], 0, 0, 0);
          }
        }
        // 6) elementwise: i,j,f,o in-lane
#pragma unroll
        for (int r = 0; r < 4; ++r) {
          float iv = acc[0][r], jv = acc[1][r], fv = acc[2][r], ov = acc[3][r];
          float cn = cst[r] * sigm(fv + 1.f) + sigm(iv) * tanh_fast(jv);
          cst[r] = cn;
          float hvv = tanh_fast(cn) * sigm(ov);
          sm.l.stage[sb][rquad * 4 + r][hb * 16 + colq] = f2b(hvv);
        }
      }
      __syncthreads();
      // 7) DEDICATED STORER WAVE: waves 0/1 proceed to step s+1 immediately;
      //    wave 2 pushes the 1KB h block, drains to LLC, sets the flag.
      if (hb == 2) {
        const int t2 = tid - 128;
        const int row = t2 >> 2, q = t2 & 3;
        union { short8 v; int4v i; } vv;
        vv.v = *(const short8*)&sm.l.stage[sb][row][q * 8];
        int* dst = hbuf + (size_t)(s + 1) * 32768 + bg * 4096 + hg * 256 + row * 16 + q * 4;
        asm volatile("global_store_dwordx4 %0, %1, off sc0 sc1"
                     :: "v"(dst), "v"(vv.i) : "memory");
        if (dec) {  // dec_hs is consumed intra-kernel by out blocks -> sc0sc1 too
          const u16* da = dec_hs + (size_t)(s - 64) * 65536 +
                          (size_t)(bg * 16 + row) * 512 + hg * 32 + q * 8;
          asm volatile("global_store_dwordx4 %0, %1, off sc0 sc1"
                       :: "v"(da), "v"(vv.i) : "memory");
        }
        asm volatile("s_waitcnt vmcnt(0)" ::: "memory");   // data acked at LLC
        if (t2 == 0) {
          int* fp = flags + ((size_t)(s + 1) * 8 + bg) * 16 + hg;
          int one = 1;
          asm volatile("global_store_dword %0, %1, off sc0 sc1"
                       :: "v"(fp), "v"(one) : "memory");
        }
      }
      if (s == 63) {   // swap to decoder W_h (cols 320..831 of WdecT)
        for (int i = tid; i < 128 * 64; i += 256) {
          int lr = i >> 6, cc = i & 63;
          const u16* src = WdecT + (size_t)((lr >> 5) * 512 + hg * 32 + (lr & 31)) * 832 + 320;
          *(short8*)&sm.l.wlds[lr][cc * 8] = *(const short8*)(src + cc * 8);
        }
        __syncthreads();
      }
    }
    asm volatile("s_waitcnt vmcnt(0)" ::: "memory");
    return;
  }

  // ------------------ producer GEMM block: 4-deep counted-vmcnt pipeline --------
  int idx = bid - 128;
  const u16* A; const u16* BT; u16* Cb = nullptr; const float* bias; int* flag = nullptr;
  int lda, ldb, K, m0, n0, mode, tcap = 0;
  if (idx < 1024) {
    int t = idx >> 4, nt = idx & 15;
    A = A_enc; lda = 2048; BT = WencT; ldb = 2560; K = 2048;
    Cb = pre_enc; bias = b_enc; flag = pf_enc + t;
    m0 = t * 128; n0 = nt * 128; mode = 0;
  } else if (idx < 1536) {
    idx -= 1024;
    int t = idx >> 4, nt = idx & 15;
    A = A_dec; lda = 320; BT = WdecT; ldb = 832; K = 320;
    Cb = pre_dec; bias = b_dec; flag = pf_dec + t;
    m0 = t * 128; n0 = nt * 128; mode = 0;
  } else {
    idx -= 1536;
    int t = idx / 3, nt = idx % 3;
    A = dec_hs; lda = 512; BT = WoutT; ldb = 512; K = 512;
    bias = b_out; m0 = t * 128; n0 = nt * 128; mode = 1; tcap = t;
    // wait until dec_hs[t] is stored & drained by all 128 LSTM blocks
    const int* wf = flags + (size_t)(tcap + 65) * 128 + (tid & 127);
    while (__hip_atomic_load(wf, __ATOMIC_RELAXED, __HIP_MEMORY_SCOPE_AGENT) == 0) {}
    asm volatile("" ::: "memory");
    __syncthreads();
  }
  const int wave = tid >> 6;
  const int wm = wave & 1, wn = wave >> 1;
  const int colq = lane & 15, rquad = lane >> 4;

  f32x4 acc[4][4];
#pragma unroll
  for (int i = 0; i < 4; ++i)
#pragma unroll
    for (int j = 0; j < 4; ++j) { f32x4 z = {0.f, 0.f, 0.f, 0.f}; acc[i][j] = z; }

  auto stage_tile = [&](int buf, int k0) {   // 4 gl2lds per wave per stage
#pragma unroll
    for (int c = 0; c < 2; ++c) {
      const int ch = wave + c * 4;
      const int slot = ch * 64 + lane;
      const int m = slot >> 2;
      const int koff = (slot & 3) * 8;
      gl2lds16(A + (size_t)(m0 + m) * lda + k0 + koff, sm.g.at[buf] + ch * 512);
      gl2lds16(BT + (size_t)(n0 + m) * ldb + k0 + koff, sm.g.bt[buf] + ch * 512);
    }
  };

  const int niter = K >> 5;                  // 64 / 10 / 16, all >= 4
  stage_tile(0, 0);
  stage_tile(1, 32);
  stage_tile(2, 64);
  for (int it = 0; it < niter; ++it) {
    if (it + 3 < niter) stage_tile((it + 3) & 3, (it + 3) << 5);
    // per-wave outstanding: 4 loads per in-flight stage; wait until stage `it` done
    const int excess = (niter - 1 - it) < 3 ? (niter - 1 - it) : 3;
    if (excess == 3)      asm volatile("s_waitcnt vmcnt(12)" ::: "memory");
    else if (excess == 2) asm volatile("s_waitcnt vmcnt(8)" ::: "memory");
    else if (excess == 1) asm volatile("s_waitcnt vmcnt(4)" ::: "memory");
    else                  asm volatile("s_waitcnt vmcnt(0)" ::: "memory");
    __builtin_amdgcn_s_barrier();            // all waves' stage-it loads landed
    __builtin_amdgcn_sched_barrier(0);
    const int cur = it & 3;
    short8 af[4], bf[4];
#pragma unroll
    for (int i = 0; i < 4; ++i)
      af[i] = *(const short8*)(sm.g.at[cur] + (wm * 64 + i * 16 + colq) * 32 + rquad * 8);
#pragma unroll
    for (int j = 0; j < 4; ++j)
      bf[j] = *(const short8*)(sm.g.bt[cur] + (wn * 64 + j * 16 + colq) * 32 + rquad * 8);
#pragma unroll
    for (int i = 0; i < 4; ++i)
#pragma unroll
      for (int j = 0; j < 4; ++j)
        acc[i][j] = __builtin_amdgcn_mfma_f32_16x16x32_bf16(af[i], bf[j], acc[i][j], 0, 0, 0);
    __builtin_amdgcn_sched_barrier(0);
    asm volatile("s_waitcnt lgkmcnt(0)" ::: "memory");
    __builtin_amdgcn_s_barrier();            // buf[it] reads done -> reusable
  }

  const int gm_base = m0 + wm * 64;
  const int gn_base = n0 + wn * 64;
  if (mode == 0) {
    // epilogue: sc0sc1 stores (intra-kernel cross-XCD visibility), drain, flag
#pragma unroll
    for (int i = 0; i < 4; ++i) {
#pragma unroll
      for (int j = 0; j < 4; ++j) {
        const int gn = gn_base + j * 16 + colq;
        const float bv = bias[gn];
        const int rbase = gm_base + i * 16 + rquad * 4;
#pragma unroll
        for (int r = 0; r < 4; ++r) {
          int hv16 = (int)f2b(acc[i][j][r] + bv);
          const u16* addr = Cb + (size_t)(rbase + r) * 2048 + gn;
          asm volatile("global_store_short %0, %1, off sc0 sc1"
                       :: "v"(addr), "v"(hv16) : "memory");
        }
      }
    }
    asm volatile("s_waitcnt vmcnt(0)" ::: "memory");
    __syncthreads();
    if (tid == 0)
      __hip_atomic_fetch_add(flag, 1, __ATOMIC_RELAXED, __HIP_MEMORY_SCOPE_AGENT);
  } else {
    // output projection epilogue: fp32, out[(b*32 + t)*300 + gn], gn < 300
#pragma unroll
    for (int i = 0; i < 4; ++i) {
#pragma unroll
      for (int j = 0; j < 4; ++j) {
        const int gn = gn_base + j * 16 + colq;
        const float bv = (gn < 300) ? bias[gn] : 0.f;
        const int rbase = gm_base + i * 16 + rquad * 4;
#pragma unroll
        for (int r = 0; r < 4; ++r) {
          const float v = acc[i][j][r] + bv;
          const int row = rbase + r;           // t*128 + b
          if (gn < 300)
            outp[(size_t)((row & 127) * 32 + (row >> 7)) * 300 + gn] = v;
        }
      }
    }
  }
}

extern "C" void kernel_launch(void* const* d_in, const int* in_sizes, int n_in,
                              void* d_out, int out_size, void* d_ws, size_t ws_size,
                              hipStream_t stream) {
  const float* frames = (const float*)d_in[0];   // [128,64,2048]
  const int* cap_ids  = (const int*)d_in[1];     // [128,32]
  const float* emb    = (const float*)d_in[2];   // [32000,300]
  const float* W_enc  = (const float*)d_in[3];   // [2560,2048]
  const float* b_enc  = (const float*)d_in[4];   // [2048]
  const float* W_dec  = (const float*)d_in[5];   // [812,2048]
  const float* b_dec  = (const float*)d_in[6];   // [2048]
  const float* W_out  = (const float*)d_in[7];   // [512,300]
  const float* b_out  = (const float*)d_in[8];   // [300]
  float* out = (float*)d_out;

  char* ws = (char*)d_ws;
  size_t off = 0;
  auto alloc = [&](size_t bytes) {
    void* p = ws + off;
    off += (bytes + 255) & ~(size_t)255;
    return p;
  };
  u16* A_enc   = (u16*)alloc(8192ull * 2048 * 2);
  u16* WencT   = (u16*)alloc(2048ull * 2560 * 2);
  u16* pre_enc = (u16*)alloc(64ull * 128 * 2048 * 2);
  u16* A_dec   = (u16*)alloc(4096ull * 320 * 2);
  u16* WdecT   = (u16*)alloc(2048ull * 832 * 2);
  u16* pre_dec = (u16*)alloc(32ull * 128 * 2048 * 2);
  u16* WoutT   = (u16*)alloc(384ull * 512 * 2);
  u16* dec_hs  = (u16*)alloc(32ull * 128 * 512 * 2);
  int* hbuf    = (int*)alloc(97ull * 32768 * 4);
  int* flags   = (int*)alloc(97ull * 8 * 16 * 4);
  int* pf      = (int*)alloc(96ull * 4);          // [64] enc + [32] dec t-flags
  int* pf_enc  = pf;
  int* pf_dec  = pf + 64;

  hipMemsetAsync(hbuf, 0, 32768ull * 4, stream);
  hipMemsetAsync(flags, 0, 97ull * 8 * 16 * 4, stream);
  hipMemsetAsync(pf, 0, 96ull * 4, stream);

  // one merged prep kernel: cvt + 2 transposes + woutT + embed
  prep_kernel<<<19872, 256, 0, stream>>>(frames, A_enc, W_enc, WencT, W_dec, WdecT,
                                         W_out, WoutT, cap_ids, emb, A_dec);

  // fused: 128 LSTM + 1024 enc-GEMM + 512 dec-GEMM + 96 out-proj blocks
  mega_kernel<<<1760, 256, 0, stream>>>(A_enc, WencT, pre_enc, b_enc,
                                        A_dec, WdecT, pre_dec, b_dec,
                                        WoutT, b_out, out,
                                        hbuf, dec_hs, flags, pf_enc, pf_dec);
}

// Round 3
// 664.920 us; speedup vs baseline: 1.0937x; 1.0036x over previous
//
#include <hip/hip_runtime.h>
#include <stdint.h>

typedef unsigned short u16;
typedef __attribute__((ext_vector_type(4))) float f32x4;
typedef __attribute__((ext_vector_type(8))) short short8;
typedef __attribute__((ext_vector_type(4))) unsigned short u16x4;
typedef __attribute__((ext_vector_type(4))) int int4v;
typedef __attribute__((ext_vector_type(2))) int int2v;

__device__ __forceinline__ u16 f2b(float f) {
  uint32_t u = __float_as_uint(f);
  uint32_t r = (u + 0x7fffu + ((u >> 16) & 1u)) >> 16;   // RNE
  return (u16)r;
}
__device__ __forceinline__ float b2f(u16 b) {
  return __uint_as_float(((uint32_t)b) << 16);
}
__device__ __forceinline__ float sigm(float x) { return 1.f / (1.f + __expf(-x)); }
__device__ __forceinline__ float tanh_fast(float x) {
  float e = __expf(2.f * x);
  return 1.f - 2.f / (e + 1.f);   // safe at +-inf
}
__device__ __forceinline__ void gl2lds16(const void* g, void* l) {
  __builtin_amdgcn_global_load_lds((const __attribute__((address_space(1))) void*)g,
                                   (__attribute__((address_space(3))) void*)l, 16, 0, 0);
}

// ================= merged prep kernel =================
__global__ __launch_bounds__(256)
void prep_kernel(const float* __restrict__ frames, u16* __restrict__ A_enc,
                 const float* __restrict__ W_enc, u16* __restrict__ WencT,
                 const float* __restrict__ W_dec, u16* __restrict__ WdecT,
                 const float* __restrict__ W_out, u16* __restrict__ WoutT,
                 const int* __restrict__ ids, const float* __restrict__ emb,
                 u16* __restrict__ Adec) {
  __shared__ float tile[64][65];
  const int bid = blockIdx.x;
  const int tid = threadIdx.x;

  if (bid < 16384) {
    // ---- cvt: A_enc row = t*128 + b ----
    int i = bid * 256 + tid;
    float4 v = ((const float4*)frames)[i];
    int e = i * 4;                 // flat elem in [128][64][2048]
    int b = e >> 17;
    int t = (e >> 11) & 63;
    int d = e & 2047;
    size_t row = (size_t)t * 128 + b;
    u16x4 o = { f2b(v.x), f2b(v.y), f2b(v.z), f2b(v.w) };
    *(u16x4*)(A_enc + row * 2048 + d) = o;
    return;
  }

  const float* W; u16* WT; int ldin, ldout, xreal, xpad, bx, by;
  if (bid < 18080) {
    if (bid < 17664) {
      int idx = bid - 16384;
      W = W_enc; WT = WencT; ldin = 2048; ldout = 2560; xreal = 2048; xpad = 2048;
      bx = idx % 40; by = idx / 40;
    } else {
      int idx = bid - 17664;
      W = W_dec; WT = WdecT; ldin = 2048; ldout = 832; xreal = 300; xpad = 320;
      bx = idx % 13; by = idx / 13;
    }
    const int kb = bx * 64;
    const int pb = by * 64;
    const int pc = tid & 63;
    const int kr4 = tid >> 6;
#pragma unroll
    for (int it = 0; it < 16; ++it) {
      int kl = kr4 + it * 4;
      int kc = kb + kl;
      int ko = kc < xpad ? kc : kc - (xpad - xreal);
      bool valid = (kc < xreal) || (kc >= xpad);
      tile[kl][pc] = valid ? W[(size_t)ko * ldin + pb + pc] : 0.f;
    }
    __syncthreads();
    const int pl = tid >> 2;
    const int kq = tid & 3;
#pragma unroll
    for (int half = 0; half < 2; ++half) {
      union { short8 v; u16 a[8]; } pk;
#pragma unroll
      for (int i = 0; i < 8; ++i) pk.a[i] = f2b(tile[kq * 16 + half * 8 + i][pl]);
      *(short8*)&WT[(size_t)(pb + pl) * ldout + kb + kq * 16 + half * 8] = pk.v;
    }
    return;
  }

  if (bid < 18848) {
    // ---- W_out -> B^T bf16 [384][512] ----
    int idx = (bid - 18080) * 256 + tid;
    int n = idx >> 9, k = idx & 511;
    float v = (n < 300) ? W_out[(size_t)k * 300 + n] : 0.f;
    WoutT[idx] = f2b(v);
    return;
  }

  // ---- embed gather: 4 rows per block ----
  int r = (bid - 18848) * 4 + (tid >> 6);   // r = t*128 + b
  int t = r >> 7, b = r & 127;
  int id = ids[b * 32 + t];
  const float* src = emb + (size_t)id * 300;
  u16* dst = Adec + (size_t)r * 320;
  for (int d = tid & 63; d < 320; d += 64)
    dst[d] = f2b(d < 300 ? src[d] : 0.f);
}

// ================= fused persistent kernel =================
// blocks 0..127     : LSTM recurrence (flag-after-drain protocol, dedicated storer wave)
// blocks 128..1151  : encoder pre-GEMM, t-major (t = (bid-128)>>4, nt = &15)
// blocks 1152..1663 : decoder pre-GEMM, t-major
// blocks 1664..1759 : output projection (waits on dflags[t] row: dedicated flag
//                     array so 96 spinning blocks never touch the h-flag lines)
//
// pre layout (PRE2, per t, 262144 u16): 32B chunk per (bg,hg,hb,rq,cq), chunk
// elem = l*4+r. Consumer lane reads its whole 16-value gate set as 2 dwordx4.
struct SmemLstm { u16 wlds[128][520]; u16 stage[2][16][32]; };
struct SmemGemm { u16 at[4][128 * 32]; u16 bt[4][128 * 32]; };   // 4-deep pipeline
union SmemU { SmemLstm l; SmemGemm g; };

__global__ __launch_bounds__(256)
void mega_kernel(const u16* __restrict__ A_enc, const u16* __restrict__ WencT,
                 u16* __restrict__ pre_enc, const float* __restrict__ b_enc,
                 const u16* __restrict__ A_dec, const u16* __restrict__ WdecT,
                 u16* __restrict__ pre_dec, const float* __restrict__ b_dec,
                 const u16* __restrict__ WoutT, const float* __restrict__ b_out,
                 float* __restrict__ outp,
                 int* __restrict__ hbuf, u16* __restrict__ dec_hs,
                 int* __restrict__ flags, int* __restrict__ pf_enc,
                 int* __restrict__ pf_dec, int* __restrict__ dflags) {
  __shared__ SmemU sm;
  const int bid = blockIdx.x;
  const int tid = threadIdx.x;
  const int lane = tid & 63;

  if (bid < 128) {
    // ------------------ LSTM block (waves 0,1 compute; 2 store; 3 idle) ---------
    const int hb = tid >> 6;
    const int bg = bid & 7;
    const int hg = bid >> 3;
    const int colq = lane & 15;
    const int rquad = lane >> 4;

    for (int i = tid; i < 128 * 64; i += 256) {
      int lr = i >> 6, cc = i & 63;
      const u16* src = WencT + (size_t)((lr >> 5) * 512 + hg * 32 + (lr & 31)) * 2560 + 2048;
      *(short8*)&sm.l.wlds[lr][cc * 8] = *(const short8*)(src + cc * 8);
    }
    __syncthreads();

    float cst[4] = {0.f, 0.f, 0.f, 0.f};
    const int brow = bg * 16 + rquad * 4;
    // chunk base (u16 index, within a t-slice) for this lane's pre gate-set
    const size_t pchunk = ((((size_t)(bg * 16 + hg) * 2 + (hb & 1)) * 4 + rquad) * 16 + colq) * 16;
    union HV { int4v i; short8 s; };
    union PR { int4v i; u16 a[8]; };
    int pf_next = 0;   // prefetched pf value for the upcoming step (0 => must poll)

    for (int s = 0; s < 96; ++s) {
      const bool dec = (s >= 64);
      const int sb = s & 1;
      if (hb < 2) {
        const u16* pre_t = dec ? (pre_dec + (size_t)(s - 64) * 262144)
                               : (pre_enc + (size_t)s * 262144);
        // 1) pre-activation readiness (16 producer n-tiles per timestep)
        if (pf_next != 16) {
          int* pf = dec ? (pf_dec + (s - 64)) : (pf_enc + s);
          while (__hip_atomic_load(pf, __ATOMIC_RELAXED, __HIP_MEMORY_SCOPE_AGENT) != 16)
            __builtin_amdgcn_s_sleep(1);
        }
        asm volatile("" ::: "memory");
        // 2) pre chunk load: 32B = 2 dwordx4 (sc0 sc1, data-after-flag)
        PR praw[2];
        const u16* p0 = pre_t + pchunk;
        asm volatile("global_load_dwordx4 %0, %1, off sc0 sc1"
                     : "=v"(praw[0].i) : "v"(p0) : "memory");
        asm volatile("global_load_dwordx4 %0, %1, off offset:16 sc0 sc1"
                     : "=v"(praw[1].i) : "v"(p0) : "memory");
        // 3) h(s) flag wait: one producer flag per lane (flag-after-drain protocol)
        if (s > 0) {
          const int* fp = flags + ((size_t)s * 8 + bg) * 16 + (lane & 15);
          while (__hip_atomic_load(fp, __ATOMIC_RELAXED, __HIP_MEMORY_SCOPE_AGENT) == 0) {}
          asm volatile("" ::: "memory");
        }
        // 4) bulk h read, issued once, after flag observation
        HV hv[16];
        const int* hread = hbuf + (size_t)s * 32768 + bg * 4096 + colq * 16 + rquad * 4;
#pragma unroll
        for (int g = 0; g < 4; ++g) {
          const int* hp = hread + g * 1024;
#pragma unroll
          for (int q = 0; q < 4; ++q)
            asm volatile("global_load_dwordx4 %0, %1, off offset:%2 sc0 sc1"
                         : "=v"(hv[g * 4 + q].i) : "v"(hp), "i"(q * 1024) : "memory");
        }
        // prefetch next step's pf flag; rides the same vmcnt(0) drain below
        if (s + 1 < 96) {
          const int* pfn = (s + 1 >= 64) ? (pf_dec + (s + 1 - 64)) : (pf_enc + (s + 1));
          pf_next = __hip_atomic_load(pfn, __ATOMIC_RELAXED, __HIP_MEMORY_SCOPE_AGENT);
        }
        asm volatile("s_waitcnt vmcnt(0)" ::: "memory");
        __builtin_amdgcn_sched_barrier(0);
#pragma unroll
        for (int kt = 0; kt < 16; ++kt) asm volatile("" : "+v"(hv[kt].i));
        asm volatile("" : "+v"(praw[0].i), "+v"(praw[1].i));
        // 5) acc init + h @ W_h
        f32x4 acc[4];
#pragma unroll
        for (int l = 0; l < 4; ++l)
#pragma unroll
          for (int r = 0; r < 4; ++r) {
            int e = l * 4 + r;
            acc[l][r] = b2f(praw[e >> 3].a[e & 7]);
          }
#pragma unroll
        for (int kt = 0; kt < 16; ++kt) {
#pragma unroll
          for (int l = 0; l < 4; ++l) {
            short8 bf = *(const short8*)&sm.l.wlds[l * 32 + hb * 16 + colq][kt * 32 + rquad * 8];
            acc[l] = __builtin_amdgcn_mfma_f32_16x16x32_bf16(hv[kt].s, bf, acc[l], 0, 0, 0);
          }
        }
        // 6) elementwise: i,j,f,o in-lane
#pragma unroll
        for (int r = 0; r < 4; ++r) {
          float iv = acc[0][r], jv = acc[1][r], fv = acc[2][r], ov = acc[3][r];
          float cn = cst[r] * sigm(fv + 1.f) + sigm(iv) * tanh_fast(jv);
          cst[r] = cn;
          float hvv = tanh_fast(cn) * sigm(ov);
          sm.l.stage[sb][rquad * 4 + r][hb * 16 + colq] = f2b(hvv);
        }
      }
      __syncthreads();
      // 7) DEDICATED STORER WAVE: waves 0/1 proceed to step s+1 immediately;
      //    wave 2 pushes the 1KB h block, drains to LLC, sets the flags.
      if (hb == 2) {
        const int t2 = tid - 128;
        const int row = t2 >> 2, q = t2 & 3;
        union { short8 v; int4v i; } vv;
        vv.v = *(const short8*)&sm.l.stage[sb][row][q * 8];
        int* dst = hbuf + (size_t)(s + 1) * 32768 + bg * 4096 + hg * 256 + row * 16 + q * 4;
        asm volatile("global_store_dwordx4 %0, %1, off sc0 sc1"
                     :: "v"(dst), "v"(vv.i) : "memory");
        if (dec) {  // dec_hs is consumed intra-kernel by out blocks -> sc0sc1 too
          const u16* da = dec_hs + (size_t)(s - 64) * 65536 +
                          (size_t)(bg * 16 + row) * 512 + hg * 32 + q * 8;
          asm volatile("global_store_dwordx4 %0, %1, off sc0 sc1"
                       :: "v"(da), "v"(vv.i) : "memory");
        }
        asm volatile("s_waitcnt vmcnt(0)" ::: "memory");   // data acked at LLC
        if (t2 == 0) {
          int* fp = flags + ((size_t)(s + 1) * 8 + bg) * 16 + hg;
          int one = 1;
          asm volatile("global_store_dword %0, %1, off sc0 sc1"
                       :: "v"(fp), "v"(one) : "memory");
        }
        if (dec && t2 == 1) {   // out-proj readiness: separate line set, off h-path
          int* dfp = dflags + (size_t)(s - 64) * 128 + bid;
          int one = 1;
          asm volatile("global_store_dword %0, %1, off sc0 sc1"
                       :: "v"(dfp), "v"(one) : "memory");
        }
      }
      if (s == 63) {   // swap to decoder W_h (cols 320..831 of WdecT)
        for (int i = tid; i < 128 * 64; i += 256) {
          int lr = i >> 6, cc = i & 63;
          const u16* src = WdecT + (size_t)((lr >> 5) * 512 + hg * 32 + (lr & 31)) * 832 + 320;
          *(short8*)&sm.l.wlds[lr][cc * 8] = *(const short8*)(src + cc * 8);
        }
        __syncthreads();
      }
    }
    asm volatile("s_waitcnt vmcnt(0)" ::: "memory");
    return;
  }

  // ------------------ producer GEMM block: 4-deep counted-vmcnt pipeline --------
  int idx = bid - 128;
  const u16* A; const u16* BT; u16* Cb = nullptr; const float* bias; int* flag = nullptr;
  int lda, ldb, K, m0, n0, mode;
  if (idx < 1024) {
    int t = idx >> 4, nt = idx & 15;
    A = A_enc; lda = 2048; BT = WencT; ldb = 2560; K = 2048;
    Cb = pre_enc + (size_t)t * 262144; bias = b_enc; flag = pf_enc + t;
    m0 = t * 128; n0 = nt * 128; mode = 0;
  } else if (idx < 1536) {
    idx -= 1024;
    int t = idx >> 4, nt = idx & 15;
    A = A_dec; lda = 320; BT = WdecT; ldb = 832; K = 320;
    Cb = pre_dec + (size_t)t * 262144; bias = b_dec; flag = pf_dec + t;
    m0 = t * 128; n0 = nt * 128; mode = 0;
  } else {
    idx -= 1536;
    int t = idx / 3, nt = idx % 3;
    A = dec_hs; lda = 512; BT = WoutT; ldb = 512; K = 512;
    bias = b_out; m0 = t * 128; n0 = nt * 128; mode = 1;
    // wait until dec_hs[t] is stored & drained by all 128 LSTM blocks.
    // dedicated dflags + s_sleep: keeps these 96 spinners off the h-flag lines.
    if (tid < 128) {
      const int* wf = dflags + (size_t)t * 128 + tid;
      while (__hip_atomic_load(wf, __ATOMIC_RELAXED, __HIP_MEMORY_SCOPE_AGENT) == 0)
        __builtin_amdgcn_s_sleep(8);
    }
    asm volatile("" ::: "memory");
    __syncthreads();
  }
  const int wave = tid >> 6;
  const int wm = wave & 1, wn = wave >> 1;
  const int colq = lane & 15, rquad = lane >> 4;

  f32x4 acc[4][4];
#pragma unroll
  for (int i = 0; i < 4; ++i)
#pragma unroll
    for (int j = 0; j < 4; ++j) { f32x4 z = {0.f, 0.f, 0.f, 0.f}; acc[i][j] = z; }

  auto stage_tile = [&](int buf, int k0) {   // 4 gl2lds per wave per stage
#pragma unroll
    for (int c = 0; c < 2; ++c) {
      const int ch = wave + c * 4;
      const int slot = ch * 64 + lane;
      const int m = slot >> 2;
      const int koff = (slot & 3) * 8;
      gl2lds16(A + (size_t)(m0 + m) * lda + k0 + koff, sm.g.at[buf] + ch * 512);
      gl2lds16(BT + (size_t)(n0 + m) * ldb + k0 + koff, sm.g.bt[buf] + ch * 512);
    }
  };

  const int niter = K >> 5;                  // 64 / 10 / 16, all >= 4
  stage_tile(0, 0);
  stage_tile(1, 32);
  stage_tile(2, 64);
  for (int it = 0; it < niter; ++it) {
    if (it + 3 < niter) stage_tile((it + 3) & 3, (it + 3) << 5);
    // per-wave outstanding: 4 loads per in-flight stage; wait until stage `it` done
    const int excess = (niter - 1 - it) < 3 ? (niter - 1 - it) : 3;
    if (excess == 3)      asm volatile("s_waitcnt vmcnt(12)" ::: "memory");
    else if (excess == 2) asm volatile("s_waitcnt vmcnt(8)" ::: "memory");
    else if (excess == 1) asm volatile("s_waitcnt vmcnt(4)" ::: "memory");
    else                  asm volatile("s_waitcnt vmcnt(0)" ::: "memory");
    __builtin_amdgcn_s_barrier();            // all waves' stage-it loads landed
    __builtin_amdgcn_sched_barrier(0);
    const int cur = it & 3;
    short8 af[4], bf[4];
#pragma unroll
    for (int i = 0; i < 4; ++i)
      af[i] = *(const short8*)(sm.g.at[cur] + (wm * 64 + i * 16 + colq) * 32 + rquad * 8);
#pragma unroll
    for (int j = 0; j < 4; ++j)
      bf[j] = *(const short8*)(sm.g.bt[cur] + (wn * 64 + j * 16 + colq) * 32 + rquad * 8);
#pragma unroll
    for (int i = 0; i < 4; ++i)
#pragma unroll
      for (int j = 0; j < 4; ++j)
        acc[i][j] = __builtin_amdgcn_mfma_f32_16x16x32_bf16(af[i], bf[j], acc[i][j], 0, 0, 0);
    __builtin_amdgcn_sched_barrier(0);
    asm volatile("s_waitcnt lgkmcnt(0)" ::: "memory");
    __builtin_amdgcn_s_barrier();            // buf[it] reads done -> reusable
  }

  const int gm_base = m0 + wm * 64;
  const int gn_base = n0 + wn * 64;
  if (mode == 0) {
    // epilogue: write PRE2 chunk layout, 16 x dwordx2 sc0sc1 stores, drain, flag
#pragma unroll
    for (int i = 0; i < 4; ++i) {
      const int bgp = wm * 4 + i;
#pragma unroll
      for (int j = 0; j < 4; ++j) {
        const int gnb = gn_base + j * 16;       // multiple of 16
        const int gn = gnb + colq;
        const float bv = bias[gn];
        const int l = gnb >> 9;
        const int hcolb = gnb & 511;
        const int hg_ = hcolb >> 5;
        const int hb_ = (hcolb >> 4) & 1;
        u16* cp = Cb + ((((size_t)(bgp * 16 + hg_) * 2 + hb_) * 4 + rquad) * 16 + colq) * 16
                     + l * 4;
        union { u16x4 h; int2v d; } pk;
#pragma unroll
        for (int r = 0; r < 4; ++r) pk.h[r] = f2b(acc[i][j][r] + bv);
        asm volatile("global_store_dwordx2 %0, %1, off sc0 sc1"
                     :: "v"(cp), "v"(pk.d) : "memory");
      }
    }
    asm volatile("s_waitcnt vmcnt(0)" ::: "memory");
    __syncthreads();
    if (tid == 0)
      __hip_atomic_fetch_add(flag, 1, __ATOMIC_RELAXED, __HIP_MEMORY_SCOPE_AGENT);
  } else {
    // output projection epilogue: fp32, out[(b*32 + t)*300 + gn], gn < 300
#pragma unroll
    for (int i = 0; i < 4; ++i) {
#pragma unroll
      for (int j = 0; j < 4; ++j) {
        const int gn = gn_base + j * 16 + colq;
        const float bv = (gn < 300) ? bias[gn] : 0.f;
        const int rbase = gm_base + i * 16 + rquad * 4;
#pragma unroll
        for (int r = 0; r < 4; ++r) {
          const float v = acc[i][j][r] + bv;
          const int row = rbase + r;           // t*128 + b
          if (gn < 300)
            outp[(size_t)((row & 127) * 32 + (row >> 7)) * 300 + gn] = v;
        }
      }
    }
  }
}

extern "C" void kernel_launch(void* const* d_in, const int* in_sizes, int n_in,
                              void* d_out, int out_size, void* d_ws, size_t ws_size,
                              hipStream_t stream) {
  const float* frames = (const float*)d_in[0];   // [128,64,2048]
  const int* cap_ids  = (const int*)d_in[1];     // [128,32]
  const float* emb    = (const float*)d_in[2];   // [32000,300]
  const float* W_enc  = (const float*)d_in[3];   // [2560,2048]
  const float* b_enc  = (const float*)d_in[4];   // [2048]
  const float* W_dec  = (const float*)d_in[5];   // [812,2048]
  const float* b_dec  = (const float*)d_in[6];   // [2048]
  const float* W_out  = (const float*)d_in[7];   // [512,300]
  const float* b_out  = (const float*)d_in[8];   // [300]
  float* out = (float*)d_out;

  char* ws = (char*)d_ws;
  size_t off = 0;
  auto alloc = [&](size_t bytes) {
    void* p = ws + off;
    off += (bytes + 255) & ~(size_t)255;
    return p;
  };
  u16* A_enc   = (u16*)alloc(8192ull * 2048 * 2);
  u16* WencT   = (u16*)alloc(2048ull * 2560 * 2);
  u16* pre_enc = (u16*)alloc(64ull * 128 * 2048 * 2);
  u16* A_dec   = (u16*)alloc(4096ull * 320 * 2);
  u16* WdecT   = (u16*)alloc(2048ull * 832 * 2);
  u16* pre_dec = (u16*)alloc(32ull * 128 * 2048 * 2);
  u16* WoutT   = (u16*)alloc(384ull * 512 * 2);
  u16* dec_hs  = (u16*)alloc(32ull * 128 * 512 * 2);
  int* hbuf    = (int*)alloc(97ull * 32768 * 4);
  int* flags   = (int*)alloc(97ull * 8 * 16 * 4);
  int* pf      = (int*)alloc(96ull * 4);          // [64] enc + [32] dec t-flags
  int* dflags  = (int*)alloc(32ull * 128 * 4);    // out-proj readiness (per t, per block)
  int* pf_enc  = pf;
  int* pf_dec  = pf + 64;

  hipMemsetAsync(hbuf, 0, 32768ull * 4, stream);
  hipMemsetAsync(flags, 0, 97ull * 8 * 16 * 4, stream);
  hipMemsetAsync(pf, 0, 96ull * 4, stream);
  hipMemsetAsync(dflags, 0, 32ull * 128 * 4, stream);

  // one merged prep kernel: cvt + 2 transposes + woutT + embed
  prep_kernel<<<19872, 256, 0, stream>>>(frames, A_enc, W_enc, WencT, W_dec, WdecT,
                                         W_out, WoutT, cap_ids, emb, A_dec);

  // fused: 128 LSTM + 1024 enc-GEMM + 512 dec-GEMM + 96 out-proj blocks
  mega_kernel<<<1760, 256, 0, stream>>>(A_enc, WencT, pre_enc, b_enc,
                                        A_dec, WdecT, pre_dec, b_dec,
                                        WoutT, b_out, out,
                                        hbuf, dec_hs, flags, pf_enc, pf_dec, dflags);
}